// Round 2
// baseline (1975.535 us; speedup 1.0000x reference)
//
#include <hip/hip_runtime.h>
#include <math.h>

// Problem constants (fixed by reference): D=128, H=8, dh=16.

typedef __attribute__((ext_vector_type(8))) short short8;   // 8 x bf16
typedef __attribute__((ext_vector_type(4))) float f32x4;

__device__ __forceinline__ unsigned short f2bf(float x) {
    unsigned int u = __float_as_uint(x);
    return (unsigned short)((u + 0x7FFFu + ((u >> 16) & 1u)) >> 16);  // RNE
}
__device__ __forceinline__ float bf2f(unsigned short h) {
    return __uint_as_float(((unsigned int)h) << 16);
}

// ---------------- QKV projection: 8 rows per block, fp32 ----------------
__global__ __launch_bounds__(128) void qkv_kernel(
    const float* __restrict__ x, const float* __restrict__ WQ,
    const float* __restrict__ WK, const float* __restrict__ WV,
    float* __restrict__ Q, float* __restrict__ K, float* __restrict__ V,
    int N)
{
    const int t = threadIdx.x;
    const int r0 = blockIdx.x * 8;
    __shared__ float xs[8][128];
#pragma unroll
    for (int r = 0; r < 8; ++r)
        xs[r][t] = (r0 + r < N) ? x[(size_t)(r0 + r) * 128 + t] : 0.f;
    __syncthreads();

    float aq[8] = {0}, ak[8] = {0}, av[8] = {0};
#pragma unroll 2
    for (int k4 = 0; k4 < 32; ++k4) {
        const float* wq = WQ + (size_t)(k4 * 4) * 128 + t;
        const float* wk = WK + (size_t)(k4 * 4) * 128 + t;
        const float* wv = WV + (size_t)(k4 * 4) * 128 + t;
        float q0 = wq[0], q1 = wq[128], q2 = wq[256], q3 = wq[384];
        float k0 = wk[0], k1 = wk[128], k2 = wk[256], k3 = wk[384];
        float v0 = wv[0], v1 = wv[128], v2 = wv[256], v3 = wv[384];
#pragma unroll
        for (int r = 0; r < 8; ++r) {
            float4 xv = *(const float4*)&xs[r][k4 * 4];
            aq[r] += xv.x * q0 + xv.y * q1 + xv.z * q2 + xv.w * q3;
            ak[r] += xv.x * k0 + xv.y * k1 + xv.z * k2 + xv.w * k3;
            av[r] += xv.x * v0 + xv.y * v1 + xv.z * v2 + xv.w * v3;
        }
    }
#pragma unroll
    for (int r = 0; r < 8; ++r) {
        if (r0 + r < N) {
            const size_t o = (size_t)(r0 + r) * 128 + t;
            Q[o] = aq[r]; K[o] = ak[r]; V[o] = av[r];
        }
    }
}

// ---------------- WE -> WE^T bf16 (once per launch) ----------------
__global__ __launch_bounds__(256) void wet_kernel(
    const float* __restrict__ WE, unsigned short* __restrict__ WEt)
{
    const int i = blockIdx.x * 256 + threadIdx.x;  // i = n*128 + k
    const int n = i >> 7, k = i & 127;
    WEt[i] = f2bf(WE[k * 128 + n]);
}

// ---------------- Eh GEMM (bf16 MFMA) + fused score epilogue ----------------
// Tile: 64 edges x 128 cols, K=128. 256 threads = 4 waves, wave -> 32x64 out.
#define ASTRIDE 136
#define BSTRIDE 136
#define ESTRIDE 132

__global__ __launch_bounds__(256, 3) void eh_score_kernel(
    const float* __restrict__ ea, const unsigned short* __restrict__ WEt,
    const float* __restrict__ Q, const float* __restrict__ K,
    const int* __restrict__ src, const int* __restrict__ dst,
    unsigned short* __restrict__ score, int E)
{
    union Sm {
        struct { unsigned short B[128 * BSTRIDE]; unsigned short A[64 * ASTRIDE]; } g;
        float eh[64 * ESTRIDE];
    };
    __shared__ Sm sm;
    const int t = threadIdx.x;
    const long e0 = (long)blockIdx.x * 64;

    // Stage B = WE^T bf16 [n][k] (32KB) into LDS, 16B chunks.
#pragma unroll
    for (int kk = 0; kk < 8; ++kk) {
        const int f = t + kk * 256;            // 2048 b128 chunks
        const int row = f >> 4, c8 = (f & 15) * 8;
        *(short8*)&sm.g.B[row * BSTRIDE + c8] = *(const short8*)&WEt[row * 128 + c8];
    }
    // Stage A = edge_attr tile fp32 -> bf16.
#pragma unroll
    for (int kk = 0; kk < 8; ++kk) {
        const int f = t + kk * 256;            // 2048 float4 chunks
        const int row = f >> 5, c4 = (f & 31) * 4;
        float4 v = make_float4(0.f, 0.f, 0.f, 0.f);
        if (e0 + row < E) v = *(const float4*)&ea[(size_t)(e0 + row) * 128 + c4];
        unsigned long long pk =  (unsigned long long)f2bf(v.x)
                              | ((unsigned long long)f2bf(v.y) << 16)
                              | ((unsigned long long)f2bf(v.z) << 32)
                              | ((unsigned long long)f2bf(v.w) << 48);
        *(unsigned long long*)&sm.g.A[row * ASTRIDE + c4] = pk;
    }
    __syncthreads();

    const int w = t >> 6, l = t & 63;
    const int rb = (w >> 1) * 32, cb = (w & 1) * 64;
    const int lr = l & 15, quad = l >> 4;

    f32x4 acc[2][4];
#pragma unroll
    for (int i = 0; i < 2; ++i)
#pragma unroll
        for (int j = 0; j < 4; ++j) acc[i][j] = (f32x4){0.f, 0.f, 0.f, 0.f};

#pragma unroll
    for (int kb = 0; kb < 4; ++kb) {
        const int k0 = kb * 32 + quad * 8;
        short8 a0 = *(const short8*)&sm.g.A[(rb + lr) * ASTRIDE + k0];
        short8 a1 = *(const short8*)&sm.g.A[(rb + 16 + lr) * ASTRIDE + k0];
        short8 b0 = *(const short8*)&sm.g.B[(cb + lr) * BSTRIDE + k0];
        short8 b1 = *(const short8*)&sm.g.B[(cb + 16 + lr) * BSTRIDE + k0];
        short8 b2 = *(const short8*)&sm.g.B[(cb + 32 + lr) * BSTRIDE + k0];
        short8 b3 = *(const short8*)&sm.g.B[(cb + 48 + lr) * BSTRIDE + k0];
        acc[0][0] = __builtin_amdgcn_mfma_f32_16x16x32_bf16(a0, b0, acc[0][0], 0, 0, 0);
        acc[0][1] = __builtin_amdgcn_mfma_f32_16x16x32_bf16(a0, b1, acc[0][1], 0, 0, 0);
        acc[0][2] = __builtin_amdgcn_mfma_f32_16x16x32_bf16(a0, b2, acc[0][2], 0, 0, 0);
        acc[0][3] = __builtin_amdgcn_mfma_f32_16x16x32_bf16(a0, b3, acc[0][3], 0, 0, 0);
        acc[1][0] = __builtin_amdgcn_mfma_f32_16x16x32_bf16(a1, b0, acc[1][0], 0, 0, 0);
        acc[1][1] = __builtin_amdgcn_mfma_f32_16x16x32_bf16(a1, b1, acc[1][1], 0, 0, 0);
        acc[1][2] = __builtin_amdgcn_mfma_f32_16x16x32_bf16(a1, b2, acc[1][2], 0, 0, 0);
        acc[1][3] = __builtin_amdgcn_mfma_f32_16x16x32_bf16(a1, b3, acc[1][3], 0, 0, 0);
    }
    __syncthreads();  // A/B dead; reuse LDS for Eh fp32

    // C/D layout (measured m89/m91): col = lane&15, row = quad*4 + reg.
#pragma unroll
    for (int mi = 0; mi < 2; ++mi)
#pragma unroll
        for (int ni = 0; ni < 4; ++ni)
#pragma unroll
            for (int r = 0; r < 4; ++r)
                sm.eh[(rb + mi * 16 + quad * 4 + r) * ESTRIDE + cb + ni * 16 + lr] =
                    acc[mi][ni][r];
    __syncthreads();

    // Score: per (edge, head) reduce over dh=16 features.
    const int f = t & 127;
    const int half = t >> 7;   // wave-uniform
    for (int p = 0; p < 32; ++p) {
        const int el = p * 2 + half;
        const long e = e0 + el;
        if (e >= E) break;
        const int si = src[e], di = dst[e];
        float pv = sm.eh[el * ESTRIDE + f] * K[(size_t)si * 128 + f] *
                   Q[(size_t)di * 128 + f] * 0.25f;   // 1/sqrt(dh)=0.25
        pv += __shfl_xor(pv, 1, 16);
        pv += __shfl_xor(pv, 2, 16);
        pv += __shfl_xor(pv, 4, 16);
        pv += __shfl_xor(pv, 8, 16);
        if ((f & 15) == 0) {
            const float sc = __expf(fminf(fmaxf(pv, -5.f), 5.f));
            score[e * 8 + (f >> 4)] = f2bf(sc);
        }
    }
}

// ---------------- msg = V[src]*score, atomics into wV (=d_out) and Z ------
__global__ __launch_bounds__(256) void scatter_kernel(
    const float* __restrict__ V, const unsigned short* __restrict__ score,
    const int* __restrict__ src, const int* __restrict__ dst,
    float* __restrict__ wV, float* __restrict__ Z, long E)
{
    const long i = (long)blockIdx.x * 256 + threadIdx.x;  // over E*32
    if (i >= E * 32) return;
    const long e = i >> 5;
    const int f = (int)(i & 31) * 4;
    const int si = src[e], di = dst[e];
    const float sc = bf2f(score[e * 8 + (f >> 4)]);
    const float4 v = *(const float4*)&V[(size_t)si * 128 + f];
    float* o = &wV[(size_t)di * 128 + f];
    atomicAdd(o + 0, v.x * sc);
    atomicAdd(o + 1, v.y * sc);
    atomicAdd(o + 2, v.z * sc);
    atomicAdd(o + 3, v.w * sc);
    if ((f & 15) == 0) atomicAdd(&Z[(size_t)di * 8 + (f >> 4)], sc);
}

// ------- h = x + wV/(Z+eps) in-place in d_out; column sums/sumsq ---------
__global__ __launch_bounds__(256) void h_stats_kernel(
    const float* __restrict__ x, const float* __restrict__ Z,
    float* hw, float* __restrict__ sums, int N)
{
    const int c = threadIdx.x & 127;
    const int half = threadIdx.x >> 7;
    float s1 = 0.f, s2 = 0.f;
    for (int r = blockIdx.x * 2 + half; r < N; r += gridDim.x * 2) {
        const float z = Z[(size_t)r * 8 + (c >> 4)];
        const size_t o = (size_t)r * 128 + c;
        const float hv = x[o] + hw[o] / (z + 1e-6f);
        hw[o] = hv;
        s1 += hv;
        s2 += hv * hv;
    }
    __shared__ float red[256];
    red[threadIdx.x] = s1;
    __syncthreads();
    if (half == 0) atomicAdd(&sums[c], s1 + red[c + 128]);
    __syncthreads();
    red[threadIdx.x] = s2;
    __syncthreads();
    if (half == 0) atomicAdd(&sums[128 + c], s2 + red[c + 128]);
}

__global__ void bn_scale_kernel(
    const float* __restrict__ sums,
    const float* __restrict__ gamma, const float* __restrict__ beta,
    float* __restrict__ sb, int N)
{
    const int c = threadIdx.x;  // 128 threads
    const float invN = 1.0f / (float)N;
    const float mean = sums[c] * invN;
    const float var = sums[128 + c] * invN - mean * mean;
    const float sc = gamma[c] * rsqrtf(var + 1e-5f);
    sb[c] = sc;
    sb[128 + c] = beta[c] - mean * sc;
}

__global__ __launch_bounds__(256) void bn_apply_kernel(
    float* hw, const float* __restrict__ sb, size_t total)
{
    __shared__ float ssb[256];
    ssb[threadIdx.x] = sb[threadIdx.x];
    __syncthreads();
    const size_t n4 = total / 4;
    float4* h4 = (float4*)hw;
    for (size_t i = (size_t)blockIdx.x * blockDim.x + threadIdx.x; i < n4;
         i += (size_t)gridDim.x * blockDim.x) {
        const int c4 = (int)(i & 31) * 4;
        float4 v = h4[i];
        v.x = v.x * ssb[c4 + 0] + ssb[128 + c4 + 0];
        v.y = v.y * ssb[c4 + 1] + ssb[128 + c4 + 1];
        v.z = v.z * ssb[c4 + 2] + ssb[128 + c4 + 2];
        v.w = v.w * ssb[c4 + 3] + ssb[128 + c4 + 3];
        h4[i] = v;
    }
}

extern "C" void kernel_launch(void* const* d_in, const int* in_sizes, int n_in,
                              void* d_out, int out_size, void* d_ws, size_t ws_size,
                              hipStream_t stream)
{
    const float* x         = (const float*)d_in[0];
    const float* edge_attr = (const float*)d_in[1];
    const float* WQ        = (const float*)d_in[2];
    const float* WK        = (const float*)d_in[3];
    const float* WV        = (const float*)d_in[4];
    const float* WE        = (const float*)d_in[5];
    const float* gamma     = (const float*)d_in[6];
    const float* beta      = (const float*)d_in[7];
    const int*   eidx      = (const int*)d_in[8];

    const int N = in_sizes[0] / 128;
    const int E = in_sizes[8] / 2;
    const int* src = eidx;       // edge_index[0]
    const int* dst = eidx + E;   // edge_index[1]

    float* ws = (float*)d_ws;
    const size_t NB = (size_t)N * 128;
    float* Q    = ws;
    float* K    = ws + NB;
    float* V    = ws + 2 * NB;
    float* Z    = ws + 3 * NB;                 // N*8
    float* sums = Z + (size_t)N * 8;           // 256
    float* sb   = sums + 256;                  // 256
    unsigned short* score = (unsigned short*)(sb + 256);   // E*8 bf16
    unsigned short* WEt   = score + (size_t)E * 8;         // 128*128 bf16
    float* out = (float*)d_out;                // doubles as wV accumulator

    hipMemsetAsync(d_out, 0, NB * sizeof(float), stream);
    hipMemsetAsync(Z, 0, ((size_t)N * 8 + 256) * sizeof(float), stream);

    qkv_kernel<<<(N + 7) / 8, 128, 0, stream>>>(x, WQ, WK, WV, Q, K, V, N);
    wet_kernel<<<64, 256, 0, stream>>>(WE, WEt);
    eh_score_kernel<<<(E + 63) / 64, 256, 0, stream>>>(edge_attr, WEt, Q, K, src, dst,
                                                       score, E);
    scatter_kernel<<<(int)(((long)E * 32 + 255) / 256), 256, 0, stream>>>(
        V, score, src, dst, out, Z, E);
    h_stats_kernel<<<1024, 256, 0, stream>>>(x, Z, out, sums, N);
    bn_scale_kernel<<<1, 128, 0, stream>>>(sums, gamma, beta, sb, N);
    bn_apply_kernel<<<2048, 256, 0, stream>>>(out, sb, NB);
}

// Round 3
// 1110.535 us; speedup vs baseline: 1.7789x; 1.7789x over previous
//
#include <hip/hip_runtime.h>
#include <math.h>

// Problem constants (fixed by reference): D=128, H=8, dh=16.

typedef __attribute__((ext_vector_type(8))) short short8;   // 8 x bf16
typedef __attribute__((ext_vector_type(4))) float f32x4;

__device__ __forceinline__ unsigned short f2bf(float x) {
    unsigned int u = __float_as_uint(x);
    return (unsigned short)((u + 0x7FFFu + ((u >> 16) & 1u)) >> 16);  // RNE
}

// ---------------- QKV projection: 8 rows per block, fp32 ----------------
__global__ __launch_bounds__(128) void qkv_kernel(
    const float* __restrict__ x, const float* __restrict__ WQ,
    const float* __restrict__ WK, const float* __restrict__ WV,
    float* __restrict__ Q, float* __restrict__ K, float* __restrict__ V,
    int N)
{
    const int t = threadIdx.x;
    const int r0 = blockIdx.x * 8;
    __shared__ float xs[8][128];
#pragma unroll
    for (int r = 0; r < 8; ++r)
        xs[r][t] = (r0 + r < N) ? x[(size_t)(r0 + r) * 128 + t] : 0.f;
    __syncthreads();

    float aq[8] = {0}, ak[8] = {0}, av[8] = {0};
#pragma unroll 2
    for (int k4 = 0; k4 < 32; ++k4) {
        const float* wq = WQ + (size_t)(k4 * 4) * 128 + t;
        const float* wk = WK + (size_t)(k4 * 4) * 128 + t;
        const float* wv = WV + (size_t)(k4 * 4) * 128 + t;
        float q0 = wq[0], q1 = wq[128], q2 = wq[256], q3 = wq[384];
        float k0 = wk[0], k1 = wk[128], k2 = wk[256], k3 = wk[384];
        float v0 = wv[0], v1 = wv[128], v2 = wv[256], v3 = wv[384];
#pragma unroll
        for (int r = 0; r < 8; ++r) {
            float4 xv = *(const float4*)&xs[r][k4 * 4];
            aq[r] += xv.x * q0 + xv.y * q1 + xv.z * q2 + xv.w * q3;
            ak[r] += xv.x * k0 + xv.y * k1 + xv.z * k2 + xv.w * k3;
            av[r] += xv.x * v0 + xv.y * v1 + xv.z * v2 + xv.w * v3;
        }
    }
#pragma unroll
    for (int r = 0; r < 8; ++r) {
        if (r0 + r < N) {
            const size_t o = (size_t)(r0 + r) * 128 + t;
            Q[o] = aq[r]; K[o] = ak[r]; V[o] = av[r];
        }
    }
}

// ---------------- WE -> WE^T bf16 (once per launch) ----------------
__global__ __launch_bounds__(256) void wet_kernel(
    const float* __restrict__ WE, unsigned short* __restrict__ WEt)
{
    const int i = blockIdx.x * 256 + threadIdx.x;  // i = n*128 + k
    const int n = i >> 7, k = i & 127;
    WEt[i] = f2bf(WE[k * 128 + n]);
}

// ---------------- Eh GEMM (bf16 MFMA) + fused score epilogue ----------------
#define ASTRIDE 136
#define BSTRIDE 136
#define ESTRIDE 132

__global__ __launch_bounds__(256, 3) void eh_score_kernel(
    const float* __restrict__ ea, const unsigned short* __restrict__ WEt,
    const float* __restrict__ Q, const float* __restrict__ K,
    const int* __restrict__ src, const int* __restrict__ dst,
    float* __restrict__ score, int E)
{
    union Sm {
        struct { unsigned short B[128 * BSTRIDE]; unsigned short A[64 * ASTRIDE]; } g;
        float eh[64 * ESTRIDE];
    };
    __shared__ Sm sm;
    const int t = threadIdx.x;
    const long e0 = (long)blockIdx.x * 64;

#pragma unroll
    for (int kk = 0; kk < 8; ++kk) {
        const int f = t + kk * 256;
        const int row = f >> 4, c8 = (f & 15) * 8;
        *(short8*)&sm.g.B[row * BSTRIDE + c8] = *(const short8*)&WEt[row * 128 + c8];
    }
#pragma unroll
    for (int kk = 0; kk < 8; ++kk) {
        const int f = t + kk * 256;
        const int row = f >> 5, c4 = (f & 31) * 4;
        float4 v = make_float4(0.f, 0.f, 0.f, 0.f);
        if (e0 + row < E) v = *(const float4*)&ea[(size_t)(e0 + row) * 128 + c4];
        unsigned long long pk =  (unsigned long long)f2bf(v.x)
                              | ((unsigned long long)f2bf(v.y) << 16)
                              | ((unsigned long long)f2bf(v.z) << 32)
                              | ((unsigned long long)f2bf(v.w) << 48);
        *(unsigned long long*)&sm.g.A[row * ASTRIDE + c4] = pk;
    }
    __syncthreads();

    const int w = t >> 6, l = t & 63;
    const int rb = (w >> 1) * 32, cb = (w & 1) * 64;
    const int lr = l & 15, quad = l >> 4;

    f32x4 acc[2][4];
#pragma unroll
    for (int i = 0; i < 2; ++i)
#pragma unroll
        for (int j = 0; j < 4; ++j) acc[i][j] = (f32x4){0.f, 0.f, 0.f, 0.f};

#pragma unroll
    for (int kb = 0; kb < 4; ++kb) {
        const int k0 = kb * 32 + quad * 8;
        short8 a0 = *(const short8*)&sm.g.A[(rb + lr) * ASTRIDE + k0];
        short8 a1 = *(const short8*)&sm.g.A[(rb + 16 + lr) * ASTRIDE + k0];
        short8 b0 = *(const short8*)&sm.g.B[(cb + lr) * BSTRIDE + k0];
        short8 b1 = *(const short8*)&sm.g.B[(cb + 16 + lr) * BSTRIDE + k0];
        short8 b2 = *(const short8*)&sm.g.B[(cb + 32 + lr) * BSTRIDE + k0];
        short8 b3 = *(const short8*)&sm.g.B[(cb + 48 + lr) * BSTRIDE + k0];
        acc[0][0] = __builtin_amdgcn_mfma_f32_16x16x32_bf16(a0, b0, acc[0][0], 0, 0, 0);
        acc[0][1] = __builtin_amdgcn_mfma_f32_16x16x32_bf16(a0, b1, acc[0][1], 0, 0, 0);
        acc[0][2] = __builtin_amdgcn_mfma_f32_16x16x32_bf16(a0, b2, acc[0][2], 0, 0, 0);
        acc[0][3] = __builtin_amdgcn_mfma_f32_16x16x32_bf16(a0, b3, acc[0][3], 0, 0, 0);
        acc[1][0] = __builtin_amdgcn_mfma_f32_16x16x32_bf16(a1, b0, acc[1][0], 0, 0, 0);
        acc[1][1] = __builtin_amdgcn_mfma_f32_16x16x32_bf16(a1, b1, acc[1][1], 0, 0, 0);
        acc[1][2] = __builtin_amdgcn_mfma_f32_16x16x32_bf16(a1, b2, acc[1][2], 0, 0, 0);
        acc[1][3] = __builtin_amdgcn_mfma_f32_16x16x32_bf16(a1, b3, acc[1][3], 0, 0, 0);
    }
    __syncthreads();  // A/B dead; reuse LDS for Eh fp32

    // C/D layout (measured m89/m91): col = lane&15, row = quad*4 + reg.
#pragma unroll
    for (int mi = 0; mi < 2; ++mi)
#pragma unroll
        for (int ni = 0; ni < 4; ++ni)
#pragma unroll
            for (int r = 0; r < 4; ++r)
                sm.eh[(rb + mi * 16 + quad * 4 + r) * ESTRIDE + cb + ni * 16 + lr] =
                    acc[mi][ni][r];
    __syncthreads();

    const int f = t & 127;
    const int half = t >> 7;   // wave-uniform
    for (int p = 0; p < 32; ++p) {
        const int el = p * 2 + half;
        const long e = e0 + el;
        if (e >= E) break;
        const int si = src[e], di = dst[e];
        float pv = sm.eh[el * ESTRIDE + f] * K[(size_t)si * 128 + f] *
                   Q[(size_t)di * 128 + f] * 0.25f;   // 1/sqrt(dh)=0.25
        pv += __shfl_xor(pv, 1, 16);
        pv += __shfl_xor(pv, 2, 16);
        pv += __shfl_xor(pv, 4, 16);
        pv += __shfl_xor(pv, 8, 16);
        if ((f & 15) == 0)
            score[e * 8 + (f >> 4)] = __expf(fminf(fmaxf(pv, -5.f), 5.f));
    }
}

// ---------------- Counting sort of edges by dst ----------------
__global__ __launch_bounds__(256) void hist_kernel(
    const int* __restrict__ dst, int* __restrict__ counts, int E)
{
    const int e = blockIdx.x * 256 + threadIdx.x;
    if (e < E) atomicAdd(&counts[dst[e]], 1);
}

// 256-chunk exclusive scan (Hillis-Steele). chunksums may be null.
__global__ __launch_bounds__(256) void scan_chunk_kernel(
    const int* __restrict__ in, int* __restrict__ excl,
    int* __restrict__ chunksums, int n)
{
    __shared__ int sm[256];
    const int t = threadIdx.x;
    const int i = blockIdx.x * 256 + t;
    const int v = (i < n) ? in[i] : 0;
    sm[t] = v;
    __syncthreads();
#pragma unroll
    for (int off = 1; off < 256; off <<= 1) {
        const int a = (t >= off) ? sm[t - off] : 0;
        __syncthreads();
        sm[t] += a;
        __syncthreads();
    }
    if (i < n) excl[i] = sm[t] - v;
    if (t == 255 && chunksums) chunksums[blockIdx.x] = sm[255];
}

__global__ __launch_bounds__(256) void add_offsets_kernel(
    int* __restrict__ excl, int* __restrict__ cursor,
    const int* __restrict__ chunkoff, int n)
{
    const int i = blockIdx.x * 256 + threadIdx.x;
    if (i < n) {
        const int v = excl[i] + chunkoff[blockIdx.x];
        excl[i] = v;      // seg_start
        cursor[i] = v;    // bump cursor for fill
    }
}

__global__ __launch_bounds__(256) void fill_perm_kernel(
    const int* __restrict__ dst, int* __restrict__ cursor,
    int* __restrict__ perm, int E)
{
    const int e = blockIdx.x * 256 + threadIdx.x;
    if (e < E) {
        const int slot = atomicAdd(&cursor[dst[e]], 1);
        perm[slot] = e;
    }
}

// -------- Segmented gather: one wave per node; fused h + BN stats --------
__global__ __launch_bounds__(256) void aggregate_kernel(
    const float* __restrict__ V, const float* __restrict__ score,
    const int* __restrict__ src, const int* __restrict__ perm,
    const int* __restrict__ seg_start, const int* __restrict__ counts,
    const float* __restrict__ x, float* __restrict__ out,
    float* __restrict__ sums, int N)
{
    const int t = threadIdx.x;
    const int w = t >> 6, lane = t & 63;
    const int ha = lane >> 4, hb = 4 + (lane >> 4);
    float s1a = 0.f, s1b = 0.f, s2a = 0.f, s2b = 0.f;

    for (int node = blockIdx.x * 4 + w; node < N; node += gridDim.x * 4) {
        const int beg = seg_start[node];
        const int cnt = counts[node];
        float acc0 = 0.f, acc1 = 0.f, za = 0.f, zb = 0.f;
        for (int j = 0; j < cnt; ++j) {
            const int e = perm[beg + j];
            const int s = src[e];
            const float sa = score[(size_t)e * 8 + ha];
            const float sb = score[(size_t)e * 8 + hb];
            acc0 += sa * V[(size_t)s * 128 + lane];
            acc1 += sb * V[(size_t)s * 128 + 64 + lane];
            za += sa; zb += sb;
        }
        const size_t o = (size_t)node * 128 + lane;
        const float hv0 = x[o] + acc0 / (za + 1e-6f);
        const float hv1 = x[o + 64] + acc1 / (zb + 1e-6f);
        out[o] = hv0;
        out[o + 64] = hv1;
        s1a += hv0; s1b += hv1;
        s2a += hv0 * hv0; s2b += hv1 * hv1;
    }

    __shared__ float red[4][128];
    red[w][lane] = s1a; red[w][lane + 64] = s1b;
    __syncthreads();
    if (t < 128) atomicAdd(&sums[t], red[0][t] + red[1][t] + red[2][t] + red[3][t]);
    __syncthreads();
    red[w][lane] = s2a; red[w][lane + 64] = s2b;
    __syncthreads();
    if (t < 128) atomicAdd(&sums[128 + t], red[0][t] + red[1][t] + red[2][t] + red[3][t]);
}

__global__ void bn_scale_kernel(
    const float* __restrict__ sums,
    const float* __restrict__ gamma, const float* __restrict__ beta,
    float* __restrict__ sb, int N)
{
    const int c = threadIdx.x;  // 128 threads
    const float invN = 1.0f / (float)N;
    const float mean = sums[c] * invN;
    const float var = sums[128 + c] * invN - mean * mean;
    const float sc = gamma[c] * rsqrtf(var + 1e-5f);
    sb[c] = sc;
    sb[128 + c] = beta[c] - mean * sc;
}

__global__ __launch_bounds__(256) void bn_apply_kernel(
    float* hw, const float* __restrict__ sb, size_t total)
{
    __shared__ float ssb[256];
    ssb[threadIdx.x] = sb[threadIdx.x];
    __syncthreads();
    const size_t n4 = total / 4;
    float4* h4 = (float4*)hw;
    for (size_t i = (size_t)blockIdx.x * blockDim.x + threadIdx.x; i < n4;
         i += (size_t)gridDim.x * blockDim.x) {
        const int c4 = (int)(i & 31) * 4;
        float4 v = h4[i];
        v.x = v.x * ssb[c4 + 0] + ssb[128 + c4 + 0];
        v.y = v.y * ssb[c4 + 1] + ssb[128 + c4 + 1];
        v.z = v.z * ssb[c4 + 2] + ssb[128 + c4 + 2];
        v.w = v.w * ssb[c4 + 3] + ssb[128 + c4 + 3];
        h4[i] = v;
    }
}

extern "C" void kernel_launch(void* const* d_in, const int* in_sizes, int n_in,
                              void* d_out, int out_size, void* d_ws, size_t ws_size,
                              hipStream_t stream)
{
    const float* x         = (const float*)d_in[0];
    const float* edge_attr = (const float*)d_in[1];
    const float* WQ        = (const float*)d_in[2];
    const float* WK        = (const float*)d_in[3];
    const float* WV        = (const float*)d_in[4];
    const float* WE        = (const float*)d_in[5];
    const float* gamma     = (const float*)d_in[6];
    const float* beta      = (const float*)d_in[7];
    const int*   eidx      = (const int*)d_in[8];

    const int N = in_sizes[0] / 128;
    const int E = in_sizes[8] / 2;
    const int* src = eidx;       // edge_index[0]
    const int* dst = eidx + E;   // edge_index[1]

    float* ws = (float*)d_ws;
    const size_t NB = (size_t)N * 128;
    float* Q     = ws;
    float* K     = ws + NB;
    float* V     = ws + 2 * NB;
    float* score = ws + 3 * NB;                 // E*8 fp32
    float* sums  = score + (size_t)E * 8;       // 256
    float* sb    = sums + 256;                  // 256
    unsigned short* WEt = (unsigned short*)(sb + 256);     // 128*128 bf16
    int* counts    = (int*)(WEt + 128 * 128);   // N
    int* seg_start = counts + N;                // N
    int* cursor    = seg_start + N;             // N
    int* chunksums = cursor + N;                // 256
    int* chunkoff  = chunksums + 256;           // 256
    int* perm      = chunkoff + 256;            // E
    float* out = (float*)d_out;

    const int nch = (N + 255) / 256;  // 196 <= 256: single-block second-level scan

    hipMemsetAsync(counts, 0, (size_t)N * sizeof(int), stream);
    hipMemsetAsync(sums, 0, 256 * sizeof(float), stream);

    qkv_kernel<<<(N + 7) / 8, 128, 0, stream>>>(x, WQ, WK, WV, Q, K, V, N);
    wet_kernel<<<64, 256, 0, stream>>>(WE, WEt);
    eh_score_kernel<<<(E + 63) / 64, 256, 0, stream>>>(edge_attr, WEt, Q, K, src, dst,
                                                       score, E);
    // counting sort by dst
    hist_kernel<<<(E + 255) / 256, 256, 0, stream>>>(dst, counts, E);
    scan_chunk_kernel<<<nch, 256, 0, stream>>>(counts, seg_start, chunksums, N);
    scan_chunk_kernel<<<1, 256, 0, stream>>>(chunksums, chunkoff, nullptr, nch);
    add_offsets_kernel<<<nch, 256, 0, stream>>>(seg_start, cursor, chunkoff, N);
    fill_perm_kernel<<<(E + 255) / 256, 256, 0, stream>>>(dst, cursor, perm, E);
    // segmented gather + h + BN stats
    aggregate_kernel<<<3200, 256, 0, stream>>>(V, score, src, perm, seg_start, counts,
                                               x, out, sums, N);
    bn_scale_kernel<<<1, 128, 0, stream>>>(sums, gamma, beta, sb, N);
    bn_apply_kernel<<<2048, 256, 0, stream>>>(out, sb, NB);
}